// Round 14
// baseline (85.152 us; speedup 1.0000x reference)
//
#include <hip/hip_runtime.h>

// ParallelLinear: out[b,t,o] = sum_i x[b,t,i] * W[t,o,i] + bias[t,o]
// B=512, T=1024, ISIZE=OSIZE=64, fp32 in/out.
//
// v14: barrier-free main loop. Realization: X has ZERO inter-wave reuse
// (each wave consumes only its own 16 rows) -- the X-LDS of v6..v13 was
// only a transpose mechanism, and the MFMA A-fragment layout is directly
// loadable from global (lane (n,kq) reads 32B contiguous; per instr the
// wave touches 16 rows x 128B = full lines). So: delete X staging, X LDS,
// and BOTH per-chunk barriers. Only W (8x reused across chunks) stays in
// LDS (16 KB). Waves run fully decoupled; next chunk's 4 b128 loads are
// prefetched ping-pong one chunk ahead; vmcnt never drained in the loop.
// W-frags deliberately read from LDS each chunk (the compiler demotes any
// hoisted frag array anyway -- R13, VGPR=72).
// Numerics: the 8x-verified 3-term bf16 hi/lo split (absmax 0.0156).

#define T_DIM 1024
#define B_DIM 512
#define KSZ 64
#define OSZ 64
#define ROWS 64
#define NCH (B_DIM / ROWS)   // 8

typedef __attribute__((ext_vector_type(8))) short short8;   // 8 bf16
typedef __attribute__((ext_vector_type(4))) float f32x4;

static __device__ __forceinline__ unsigned short f2bf(float f) {
    unsigned u = __float_as_uint(f);
    u += 0x7FFFu + ((u >> 16) & 1u);          // RNE
    return (unsigned short)(u >> 16);
}
static __device__ __forceinline__ float bf2f(unsigned short h) {
    return __uint_as_float((unsigned)h << 16);
}

// lgkm-only barrier: LDS ordering preserved, global loads stay in flight.
#define LGKM_BARRIER() do {                                   \
    asm volatile("s_waitcnt lgkmcnt(0)" ::: "memory");        \
    __builtin_amdgcn_s_barrier();                             \
} while (0)

__global__ __launch_bounds__(256, 4) void pl_kernel(
    const float* __restrict__ x,
    const float* __restrict__ W,
    const float* __restrict__ bias,
    float* __restrict__ out)
{
    __shared__ short Wh[OSZ * KSZ];    // 8 KB (swizzled bf16 hi plane)
    __shared__ short Wl[OSZ * KSZ];    // 8 KB  -> 16 KB total

    const int t   = blockIdx.x;        // 0..1023, one block per t
    const int tid = threadIdx.x;

    // staging coords (verified): thread = (row sr, 16-float chunk kc)
    const int sr = tid >> 2;           // 0..63
    const int kc = tid & 3;            // 0..3
    // compute coords (verified)
    const int w  = tid >> 6;           // wave 0..3 -> rows 16w..16w+15 of chunk
    const int l  = tid & 63;
    const int n  = l & 15;
    const int kq = l >> 4;             // 0..3

    // ---- W global loads FIRST (so chunk-0 prefetch stays behind them in FIFO) ----
    const float* wp = W + (size_t)t * (OSZ * KSZ) + (size_t)sr * KSZ + 16 * kc;
    float4 g0 = *(const float4*)(wp);
    float4 g1 = *(const float4*)(wp + 4);
    float4 g2 = *(const float4*)(wp + 8);
    float4 g3 = *(const float4*)(wp + 12);

    // ---- prefetch chunk 0 A-frag directly from global ----
    // lane (n,kq): x[16w+n][t][kq*8 .. ] ; ks=1 adds 32 floats
    const float* xA = x + ((size_t)(16 * w + n) * T_DIM + t) * KSZ + kq * 8;
    const size_t cstep = (size_t)ROWS * T_DIM * KSZ;   // 64 b-rows
    float4 pa0 = *(const float4*)(xA);
    float4 pa1 = *(const float4*)(xA + 4);
    float4 pa2 = *(const float4*)(xA + 32);
    float4 pa3 = *(const float4*)(xA + 36);

    // ---- convert & stage W planes (vmcnt waits only the W loads) ----
    {
        float a[8]  = {g0.x, g0.y, g0.z, g0.w, g1.x, g1.y, g1.z, g1.w};
        float b2[8] = {g2.x, g2.y, g2.z, g2.w, g3.x, g3.y, g3.z, g3.w};
        short8 h0, l0, h1, l1;
        #pragma unroll
        for (int j = 0; j < 8; ++j) {
            unsigned short hh = f2bf(a[j]);
            h0[j] = (short)hh; l0[j] = (short)f2bf(a[j] - bf2f(hh));
            unsigned short h2 = f2bf(b2[j]);
            h1[j] = (short)h2; l1[j] = (short)f2bf(b2[j] - bf2f(h2));
        }
        const int p0 = (((2 * kc)     ^ (sr & 7)) << 3);
        const int p1 = (((2 * kc + 1) ^ (sr & 7)) << 3);
        *(short8*)&Wh[sr * KSZ + p0] = h0;
        *(short8*)&Wl[sr * KSZ + p0] = l0;
        *(short8*)&Wh[sr * KSZ + p1] = h1;
        *(short8*)&Wl[sr * KSZ + p1] = l1;
    }

    LGKM_BARRIER();    // the ONLY barrier in the kernel; vmcnt untouched

    // hoist bias
    float bv[4];
    #pragma unroll
    for (int ct = 0; ct < 4; ++ct)
        bv[ct] = bias[(size_t)t * OSZ + 16 * ct + n];

    #pragma unroll 2
    for (int c = 0; c < NCH; ++c) {
        // ---- issue chunk c+1 loads (newer in FIFO; consuming pa won't drain them)
        float4 na0, na1, na2, na3;
        if (c + 1 < NCH) {
            const float* xn = xA + (size_t)(c + 1) * cstep;
            na0 = *(const float4*)(xn);
            na1 = *(const float4*)(xn + 4);
            na2 = *(const float4*)(xn + 32);
            na3 = *(const float4*)(xn + 36);
        }

        // ---- convert chunk c A-frag in registers ----
        float a[16] = {pa0.x, pa0.y, pa0.z, pa0.w, pa1.x, pa1.y, pa1.z, pa1.w,
                       pa2.x, pa2.y, pa2.z, pa2.w, pa3.x, pa3.y, pa3.z, pa3.w};
        short8 ah0, al0, ah1, al1;
        #pragma unroll
        for (int j = 0; j < 8; ++j) {
            unsigned short hh = f2bf(a[j]);
            ah0[j] = (short)hh; al0[j] = (short)f2bf(a[j] - bf2f(hh));
            unsigned short h2 = f2bf(a[8 + j]);
            ah1[j] = (short)h2; al1[j] = (short)f2bf(a[8 + j] - bf2f(h2));
        }

        // ---- MFMA: W-frags streamed from LDS (verified conflict-free) ----
        f32x4 acc[4] = {};
        #pragma unroll
        for (int ct = 0; ct < 4; ++ct) {
            const int brow = 16 * ct + n;
            {
                const int pos = (kq ^ (brow & 7)) << 3;             // ks=0
                short8 bh = *(const short8*)&Wh[brow * KSZ + pos];
                short8 bl = *(const short8*)&Wl[brow * KSZ + pos];
                acc[ct] = __builtin_amdgcn_mfma_f32_16x16x32_bf16(ah0, bh, acc[ct], 0, 0, 0);
                acc[ct] = __builtin_amdgcn_mfma_f32_16x16x32_bf16(al0, bh, acc[ct], 0, 0, 0);
                acc[ct] = __builtin_amdgcn_mfma_f32_16x16x32_bf16(ah0, bl, acc[ct], 0, 0, 0);
            }
            {
                const int pos = ((4 + kq) ^ (brow & 7)) << 3;       // ks=1
                short8 bh = *(const short8*)&Wh[brow * KSZ + pos];
                short8 bl = *(const short8*)&Wl[brow * KSZ + pos];
                acc[ct] = __builtin_amdgcn_mfma_f32_16x16x32_bf16(ah1, bh, acc[ct], 0, 0, 0);
                acc[ct] = __builtin_amdgcn_mfma_f32_16x16x32_bf16(al1, bh, acc[ct], 0, 0, 0);
                acc[ct] = __builtin_amdgcn_mfma_f32_16x16x32_bf16(ah1, bl, acc[ct], 0, 0, 0);
            }
        }

        // ---- epilogue (verified C/D map: col = n, row = 4*kq + j) ----
        const int row0 = c * ROWS;
        #pragma unroll
        for (int ct = 0; ct < 4; ++ct) {
            #pragma unroll
            for (int j = 0; j < 4; ++j) {
                const size_t b = (size_t)row0 + 16 * w + 4 * kq + j;
                out[(b * T_DIM + t) * OSZ + 16 * ct + n] = acc[ct][j] + bv[ct];
            }
        }

        if (c + 1 < NCH) { pa0 = na0; pa1 = na1; pa2 = na2; pa3 = na3; }
    }
}

extern "C" void kernel_launch(void* const* d_in, const int* in_sizes, int n_in,
                              void* d_out, int out_size, void* d_ws, size_t ws_size,
                              hipStream_t stream) {
    const float* x    = (const float*)d_in[0];
    const float* W    = (const float*)d_in[1];
    const float* bias = (const float*)d_in[2];
    float* out        = (float*)d_out;

    dim3 grid(T_DIM);                    // 1024 blocks, one per t, 4/CU
    dim3 block(256);
    pl_kernel<<<grid, block, 0, stream>>>(x, W, bias, out);
}

// Round 15
// 66.131 us; speedup vs baseline: 1.2876x; 1.2876x over previous
//
#include <hip/hip_runtime.h>

// ParallelLinear: out[b,t,o] = sum_i x[b,t,i] * W[t,o,i] + bias[t,o]
// B=512, T=1024, ISIZE=OSIZE=64, fp32 in/out.
//
// v15 = v12 (64.4us best: persistent per-t, single X buffer, lgkm-only
// barriers) + 2-deep UNCONDITIONAL register prefetch.
//  - v12's residual: 1-deep prefetch covers ~650-900cy < ~900cy HBM
//    latency -> partial exposure every chunk; and its conditional issue
//    (if c+1<NCH) blocks precise static vmcnt counting (v14 showed where
//    that leads: waits that drain stores).
//  - v15: pa=chunk c, qa=chunk c+1 in flight; after converting pa, its
//    registers re-issue chunk min(c+2,NCH-1) unconditionally (clamped
//    address; tail re-loads are L3-hot, data unused-or-identical). Loads
//    are always issued BEFORE the same iteration's stores -> prefetch
//    waits never sit behind store completion in the vmcnt FIFO.
//  - Cover: ~2 full iterations (~1500cy) > HBM latency.
// Grid 1024 = exactly 4 blocks/CU (32KB LDS), all co-resident.
// Numerics: the verified 3-term bf16 hi/lo split (absmax 0.0156).

#define T_DIM 1024
#define B_DIM 512
#define KSZ 64
#define OSZ 64
#define ROWS 64
#define NCH (B_DIM / ROWS)   // 8

typedef __attribute__((ext_vector_type(8))) short short8;   // 8 bf16
typedef __attribute__((ext_vector_type(4))) float f32x4;

static __device__ __forceinline__ unsigned short f2bf(float f) {
    unsigned u = __float_as_uint(f);
    u += 0x7FFFu + ((u >> 16) & 1u);          // RNE
    return (unsigned short)(u >> 16);
}
static __device__ __forceinline__ float bf2f(unsigned short h) {
    return __uint_as_float((unsigned)h << 16);
}

// lgkm-only barrier: LDS ordering preserved, global loads stay in flight.
#define LGKM_BARRIER() do {                                   \
    asm volatile("s_waitcnt lgkmcnt(0)" ::: "memory");        \
    __builtin_amdgcn_s_barrier();                             \
} while (0)

__global__ __launch_bounds__(256, 4) void pl_kernel(
    const float* __restrict__ x,
    const float* __restrict__ W,
    const float* __restrict__ bias,
    float* __restrict__ out)
{
    __shared__ short Xh[ROWS * KSZ];   // 8 KB  (swizzled bf16 hi plane)
    __shared__ short Xl[ROWS * KSZ];   // 8 KB
    __shared__ short Wh[OSZ * KSZ];    // 8 KB
    __shared__ short Wl[OSZ * KSZ];    // 8 KB   -> 32 KB total, 4 blocks/CU

    const int t   = blockIdx.x;        // 0..1023, persistent per t
    const int tid = threadIdx.x;

    // staging coords (verified): thread = (row sr, 16-float chunk kc)
    const int sr = tid >> 2;           // 0..63
    const int kc = tid & 3;            // 0..3
    // compute coords (verified)
    const int w  = tid >> 6;           // wave 0..3
    const int l  = tid & 63;
    const int n  = l & 15;
    const int kq = l >> 4;             // 0..3

    const size_t cstep = (size_t)ROWS * T_DIM * KSZ;   // floats per 64-row chunk
    const float* xp0 = x + ((size_t)sr * T_DIM + t) * KSZ + 16 * kc;

    // ---- prefetch chunks 0 and 1 (both in flight under W staging) ----
    float4 pa0 = *(const float4*)(xp0);
    float4 pa1 = *(const float4*)(xp0 + 4);
    float4 pa2 = *(const float4*)(xp0 + 8);
    float4 pa3 = *(const float4*)(xp0 + 12);
    float4 qa0 = *(const float4*)(xp0 + cstep);
    float4 qa1 = *(const float4*)(xp0 + cstep + 4);
    float4 qa2 = *(const float4*)(xp0 + cstep + 8);
    float4 qa3 = *(const float4*)(xp0 + cstep + 12);

    const int p0 = (((2 * kc)     ^ (sr & 7)) << 3);
    const int p1 = (((2 * kc + 1) ^ (sr & 7)) << 3);

    // ---- stage W[t] once (verified swizzle, conflict-free) ----
    {
        const float* wp = W + (size_t)t * (OSZ * KSZ) + (size_t)sr * KSZ + 16 * kc;
        float4 g0 = *(const float4*)(wp);
        float4 g1 = *(const float4*)(wp + 4);
        float4 g2 = *(const float4*)(wp + 8);
        float4 g3 = *(const float4*)(wp + 12);
        float a[8]  = {g0.x, g0.y, g0.z, g0.w, g1.x, g1.y, g1.z, g1.w};
        float b2[8] = {g2.x, g2.y, g2.z, g2.w, g3.x, g3.y, g3.z, g3.w};
        short8 h0, l0, h1, l1;
        #pragma unroll
        for (int j = 0; j < 8; ++j) {
            unsigned short hh = f2bf(a[j]);
            h0[j] = (short)hh; l0[j] = (short)f2bf(a[j] - bf2f(hh));
            unsigned short h2 = f2bf(b2[j]);
            h1[j] = (short)h2; l1[j] = (short)f2bf(b2[j] - bf2f(h2));
        }
        *(short8*)&Wh[sr * KSZ + p0] = h0;
        *(short8*)&Wl[sr * KSZ + p0] = l0;
        *(short8*)&Wh[sr * KSZ + p1] = h1;
        *(short8*)&Wl[sr * KSZ + p1] = l1;
    }

    // hoist bias (per-thread, 4 scalars)
    float bv[4];
    #pragma unroll
    for (int ct = 0; ct < 4; ++ct)
        bv[ct] = bias[(size_t)t * OSZ + 16 * ct + n];

    #pragma unroll 2
    for (int c = 0; c < NCH; ++c) {
        // ---- convert chunk c (waits vmcnt only for pa: oldest outstanding) ----
        float a[8]  = {pa0.x, pa0.y, pa0.z, pa0.w, pa1.x, pa1.y, pa1.z, pa1.w};
        float b2[8] = {pa2.x, pa2.y, pa2.z, pa2.w, pa3.x, pa3.y, pa3.z, pa3.w};
        short8 h0, l0, h1, l1;
        #pragma unroll
        for (int j = 0; j < 8; ++j) {
            unsigned short hh = f2bf(a[j]);
            h0[j] = (short)hh; l0[j] = (short)f2bf(a[j] - bf2f(hh));
            unsigned short h2 = f2bf(b2[j]);
            h1[j] = (short)h2; l1[j] = (short)f2bf(b2[j] - bf2f(h2));
        }

        if (c > 0) LGKM_BARRIER();       // all waves done reading Xs(c-1)

        *(short8*)&Xh[sr * KSZ + p0] = h0;
        *(short8*)&Xl[sr * KSZ + p0] = l0;
        *(short8*)&Xh[sr * KSZ + p1] = h1;
        *(short8*)&Xl[sr * KSZ + p1] = l1;

        // ---- re-issue pa registers with chunk min(c+2, NCH-1): UNCONDITIONAL,
        //      issued before this iteration's stores -> precise vmcnt counting.
        {
            const int cc = (c + 2 < NCH) ? (c + 2) : (NCH - 1);
            const float* xp = xp0 + (size_t)cc * cstep;
            pa0 = *(const float4*)(xp);
            pa1 = *(const float4*)(xp + 4);
            pa2 = *(const float4*)(xp + 8);
            pa3 = *(const float4*)(xp + 12);
        }

        LGKM_BARRIER();                  // Xs(c) visible; vmcnt untouched

        // ---- compute (verified): A-frags + 24 MFMA ----
        const int arow = 16 * w + n;
        short8 ah[2], al[2];
        #pragma unroll
        for (int ks = 0; ks < 2; ++ks) {
            const int pos = ((ks * 4 + kq) ^ (arow & 7)) << 3;
            ah[ks] = *(const short8*)&Xh[arow * KSZ + pos];
            al[ks] = *(const short8*)&Xl[arow * KSZ + pos];
        }

        f32x4 acc[4] = {};
        #pragma unroll
        for (int ct = 0; ct < 4; ++ct) {
            const int brow = 16 * ct + n;
            #pragma unroll
            for (int ks = 0; ks < 2; ++ks) {
                const int pos = ((ks * 4 + kq) ^ (brow & 7)) << 3;
                short8 bh = *(const short8*)&Wh[brow * KSZ + pos];
                short8 bl = *(const short8*)&Wl[brow * KSZ + pos];
                acc[ct] = __builtin_amdgcn_mfma_f32_16x16x32_bf16(ah[ks], bh, acc[ct], 0, 0, 0);
                acc[ct] = __builtin_amdgcn_mfma_f32_16x16x32_bf16(al[ks], bh, acc[ct], 0, 0, 0);
                acc[ct] = __builtin_amdgcn_mfma_f32_16x16x32_bf16(ah[ks], bl, acc[ct], 0, 0, 0);
            }
        }

        // ---- epilogue (verified C/D map: col = n, row = 4*kq + j) ----
        const int row0 = c * ROWS;
        #pragma unroll
        for (int ct = 0; ct < 4; ++ct) {
            #pragma unroll
            for (int j = 0; j < 4; ++j) {
                const size_t b = (size_t)row0 + 16 * w + 4 * kq + j;
                out[(b * T_DIM + t) * OSZ + 16 * ct + n] = acc[ct][j] + bv[ct];
            }
        }

        // ---- rotate prefetch sets: next iter's pa = qa (chunk c+1) ----
        float4 s0 = qa0, s1 = qa1, s2 = qa2, s3 = qa3;
        qa0 = pa0; qa1 = pa1; qa2 = pa2; qa3 = pa3;
        pa0 = s0;  pa1 = s1;  pa2 = s2;  pa3 = s3;
    }
}

extern "C" void kernel_launch(void* const* d_in, const int* in_sizes, int n_in,
                              void* d_out, int out_size, void* d_ws, size_t ws_size,
                              hipStream_t stream) {
    const float* x    = (const float*)d_in[0];
    const float* W    = (const float*)d_in[1];
    const float* bias = (const float*)d_in[2];
    float* out        = (float*)d_out;

    dim3 grid(T_DIM);                    // 1024 persistent blocks, 4/CU
    dim3 block(256);
    pl_kernel<<<grid, block, 0, stream>>>(x, W, bias, out);
}